// Round 1
// baseline (193.631 us; speedup 1.0000x reference)
//
#include <hip/hip_runtime.h>

typedef float v4f __attribute__((ext_vector_type(4)));

#define NB 8
#define NH 128
#define NW 128
#define NC 64
#define NF 64
#define NTAP 9

// Tile: 8 rows x 16 cols = 128 pixels, all 64 F per block.
// 256 threads. Phase 1: thread t -> pixel t/2, channel half (t&1)*32.
// Phase 2: tp = t&31 owns 4 pixels, tf = t>>5 owns 8 f; acc[4][8] in regs.
__global__ __launch_bounds__(256)
void dconv2d_fp32(const float* __restrict__ xin,
                  const float* __restrict__ offs,
                  const float* __restrict__ wt,
                  const float* __restrict__ bias,
                  float* __restrict__ out)
{
    __shared__ float s_lds[NC][128];   // sampled, c-major: s[c][pixel]
    __shared__ float w_lds[NC * NF];   // W[k]: [c][f]

    const int t  = threadIdx.x;
    const int b  = blockIdx.z;
    const int h0 = blockIdx.y * 8;
    const int w0 = blockIdx.x * 16;

    // phase-2 ids
    const int tp = t & 31;
    const int tf = t >> 5;

    // phase-1 ids
    const int p1 = t >> 1;
    const int ch = (t & 1) << 5;           // 0 or 32
    const int h  = h0 + (p1 >> 4);
    const int w  = w0 + (p1 & 15);
    const float* offp = offs + ((b * NH + h) * NW + w) * (2 * NTAP);

    float acc[4][8];
#pragma unroll
    for (int i = 0; i < 4; i++)
#pragma unroll
        for (int j = 0; j < 8; j++) acc[i][j] = 0.f;

    for (int k = 0; k < NTAP; k++) {
        // ---- stage W[k] (4096 floats) into LDS, coalesced float4 ----
        {
            const v4f* src = (const v4f*)(wt + k * NC * NF);
            v4f* dst = (v4f*)w_lds;
#pragma unroll
            for (int i = 0; i < 4; i++) dst[i * 256 + t] = src[i * 256 + t];
        }
        // ---- bilinear sample 32 channels of pixel p1 at tap k ----
        {
            const int ky = k / 3, kx = k - 3 * ky;
            float cy = (float)(h - 1 + ky) + offp[2 * k];
            float cx = (float)(w - 1 + kx) + offp[2 * k + 1];
            cy = fminf(fmaxf(cy, 0.f), (float)(NH - 1));
            cx = fminf(fmaxf(cx, 0.f), (float)(NW - 1));
            float fy0 = floorf(cy), fx0 = floorf(cx);
            int y0 = (int)fy0,        x0i = (int)fx0;
            int y1 = (int)ceilf(cy),  x1i = (int)ceilf(cx);
            float fy = cy - fy0, fx = cx - fx0;
            const float* r00 = xin + ((b * NH + y0) * NW + x0i) * NC + ch;
            const float* r10 = xin + ((b * NH + y1) * NW + x0i) * NC + ch;
            const float* r01 = xin + ((b * NH + y0) * NW + x1i) * NC + ch;
            const float* r11 = xin + ((b * NH + y1) * NW + x1i) * NC + ch;
#pragma unroll
            for (int i = 0; i < 8; i++) {
                v4f v00 = *(const v4f*)(r00 + 4 * i);
                v4f v10 = *(const v4f*)(r10 + 4 * i);
                v4f v01 = *(const v4f*)(r01 + 4 * i);
                v4f v11 = *(const v4f*)(r11 + 4 * i);
                v4f vt = v00 + (v10 - v00) * fy;
                v4f vb = v01 + (v11 - v01) * fy;
                v4f sv = vt + (vb - vt) * fx;
#pragma unroll
                for (int e = 0; e < 4; e++) s_lds[ch + 4 * i + e][p1] = sv[e];
            }
        }
        __syncthreads();
        // ---- GEMM phase: acc[p][f] += s[c][p] * w[c][f] over c ----
        {
            const float* sp = &s_lds[0][0] + 4 * tp;
            const float* wp = w_lds + 8 * tf;
#pragma unroll 4
            for (int c = 0; c < NC; c++) {
                v4f s4 = *(const v4f*)(sp + c * 128);
                v4f wa = *(const v4f*)(wp + c * NF);
                v4f wb = *(const v4f*)(wp + c * NF + 4);
#pragma unroll
                for (int i = 0; i < 4; i++) {
#pragma unroll
                    for (int j = 0; j < 4; j++) {
                        acc[i][j]     += s4[i] * wa[j];
                        acc[i][j + 4] += s4[i] * wb[j];
                    }
                }
            }
        }
        __syncthreads();
    }

    // ---- epilogue: add bias, store ----
    v4f b0 = *(const v4f*)(bias + 8 * tf);
    v4f b1 = *(const v4f*)(bias + 8 * tf + 4);
#pragma unroll
    for (int i = 0; i < 4; i++) {
        const int p  = 4 * tp + i;
        const int hh = h0 + (p >> 4);
        const int ww = w0 + (p & 15);
        float* op = out + ((b * NH + hh) * NW + ww) * NF + 8 * tf;
        v4f o0, o1;
#pragma unroll
        for (int j = 0; j < 4; j++) { o0[j] = acc[i][j] + b0[j]; o1[j] = acc[i][j + 4] + b1[j]; }
        *(v4f*)op       = o0;
        *(v4f*)(op + 4) = o1;
    }
}

extern "C" void kernel_launch(void* const* d_in, const int* in_sizes, int n_in,
                              void* d_out, int out_size, void* d_ws, size_t ws_size,
                              hipStream_t stream) {
    const float* xin  = (const float*)d_in[0];
    const float* offs = (const float*)d_in[1];
    const float* wt   = (const float*)d_in[2];
    const float* bias = (const float*)d_in[3];
    float* out = (float*)d_out;
    dim3 grid(NW / 16, NH / 8, NB);   // 8 x 16 x 8 = 1024 blocks
    dconv2d_fp32<<<grid, 256, 0, stream>>>(xin, offs, wt, bias, out);
}

// Round 2
// 67.008 us; speedup vs baseline: 2.8897x; 2.8897x over previous
//
#include <hip/hip_runtime.h>

typedef float v4f __attribute__((ext_vector_type(4)));
typedef unsigned int uint;
typedef unsigned short ushort;
typedef __attribute__((ext_vector_type(4))) uint u32x4;
typedef __attribute__((ext_vector_type(8))) ushort u16x8;
typedef __attribute__((ext_vector_type(8))) __bf16 bf16x8;
typedef __attribute__((ext_vector_type(16))) float f32x16;

#define NB 8
#define NH 128
#define NW 128
#define NC 64
#define NF 64
#define NTAP 9

__device__ __forceinline__ ushort f2bf(float f) {
    uint u = __float_as_uint(f);
    return (ushort)((u + 0x7fffu + ((u >> 16) & 1u)) >> 16);   // RNE
}
__device__ __forceinline__ float bf2f(ushort s) {
    return __uint_as_float(((uint)s) << 16);
}
__device__ __forceinline__ void g2lds16(const void* g, void* l) {
    __builtin_amdgcn_global_load_lds((__attribute__((address_space(1))) void*)(uintptr_t)g,
                                     (__attribute__((address_space(3))) void*)l, 16, 0, 0);
}

// ---- prep: x fp32 -> bf16 (halves gather traffic) ----
__global__ __launch_bounds__(256) void cvt_x_kernel(const float* __restrict__ x,
                                                    ushort* __restrict__ xb) {
    int i = blockIdx.x * 256 + threadIdx.x;          // one thread = 8 elems
    const v4f* src = (const v4f*)x + 2 * (size_t)i;
    v4f a = src[0], b = src[1];
    u16x8 o;
#pragma unroll
    for (int j = 0; j < 4; j++) { o[j] = f2bf(a[j]); o[4 + j] = f2bf(b[j]); }
    *(u16x8*)(xb + 8 * (size_t)i) = o;
}

// ---- prep: W [k][c][f] fp32 -> bf16 image [k][f][c], XOR-swizzled granules ----
// granule = 8 bf16 (16B). phys_granule = (c>>3) ^ (f&7). Linear LDS copy of this
// image reproduces the swizzled layout the GEMM-phase reads expect.
__global__ __launch_bounds__(256) void prep_w_kernel(const float* __restrict__ wt,
                                                     ushort* __restrict__ wimg) {
    int idx = blockIdx.x * 256 + threadIdx.x;        // 9*64*64 = 36864
    int c = idx & 63, f = (idx >> 6) & 63, k = idx >> 12;
    int pg = (c >> 3) ^ (f & 7);
    wimg[(k * 64 + f) * 64 + pg * 8 + (c & 7)] = f2bf(wt[(k * 64 + c) * 64 + f]);
}

// ---- main: 128-pixel (8h x 16w) x 64-F tile, 4 waves, 32x64 slab per wave ----
template<bool PREP>
__global__ __launch_bounds__(256)
void dconv2d_mfma(const void* __restrict__ xin,     // PREP: bf16 copy, else fp32
                  const float* __restrict__ offs,
                  const void* __restrict__ wsrc,    // PREP: swizzled bf16 image, else fp32 W
                  const float* __restrict__ bias,
                  float* __restrict__ out)
{
    __shared__ ushort sA[128 * 64];   // sampled [p][c] bf16, swizzled: 16 KB
    __shared__ ushort sW[64 * 64];    // W-tap   [f][c] bf16, swizzled:  8 KB

    const int t  = threadIdx.x;
    const int bb = blockIdx.z;
    const int h0 = blockIdx.y * 8;
    const int w0 = blockIdx.x * 16;

    // sampling ids: 2 threads per pixel (channel halves)
    const int p1 = t >> 1;
    const int ch = (t & 1) << 5;
    const int h  = h0 + (p1 >> 4);
    const int w  = w0 + (p1 & 15);
    const float* offp = offs + ((size_t)(bb * NH + h) * NW + w) * (2 * NTAP);

    // GEMM ids
    const int lane = t & 63, wv = t >> 6;
    const int arow = wv * 32 + (lane & 31);
    const int kh   = lane >> 5;                      // k-granule half
    const float bv0 = bias[lane & 31];
    const float bv1 = bias[32 + (lane & 31)];

    f32x16 acc0 = (f32x16)0.0f, acc1 = (f32x16)0.0f;

    for (int k = 0; k < NTAP; k++) {
        // ---- stage W[k] into sW ----
        if constexpr (PREP) {
            const char* gbase = (const char*)wsrc + (size_t)k * 8192;
#pragma unroll
            for (int it = 0; it < 2; it++)
                g2lds16(gbase + it * 4096 + t * 16, (char*)sW + it * 4096 + wv * 1024);
        } else {
            const float* wsf = (const float*)wsrc + (size_t)k * 4096;
#pragma unroll
            for (int it = 0; it < 4; it++) {
                int c = it * 16 + (t >> 4);
                int f4 = (t & 15) * 4;
                v4f v = *(const v4f*)(wsf + c * 64 + f4);
#pragma unroll
                for (int j = 0; j < 4; j++) {
                    int f = f4 + j;
                    sW[f * 64 + (((c >> 3) ^ (f & 7)) << 3) + (c & 7)] = f2bf(v[j]);
                }
            }
        }

        // ---- bilinear-sample 32 channels of pixel p1 at tap k -> sA ----
        {
            const int ky = k / 3, kx = k - 3 * ky;
            float cy = (float)(h - 1 + ky) + offp[2 * k];
            float cx = (float)(w - 1 + kx) + offp[2 * k + 1];
            cy = fminf(fmaxf(cy, 0.f), (float)(NH - 1));
            cx = fminf(fmaxf(cx, 0.f), (float)(NW - 1));
            float fy0 = floorf(cy), fx0 = floorf(cx);
            int y0 = (int)fy0,       x0i = (int)fx0;
            int y1 = (int)ceilf(cy), x1i = (int)ceilf(cx);
            float fy = cy - fy0, fx = cx - fx0;
            int i00 = ((bb * NH + y0) * NW + x0i) * NC + ch;
            int i10 = ((bb * NH + y1) * NW + x0i) * NC + ch;
            int i01 = ((bb * NH + y0) * NW + x1i) * NC + ch;
            int i11 = ((bb * NH + y1) * NW + x1i) * NC + ch;
#pragma unroll
            for (int i = 0; i < 4; i++) {           // 8 channels per iter
                float v00[8], v10[8], v01[8], v11[8];
                if constexpr (PREP) {
                    const ushort* xb = (const ushort*)xin;
                    u16x8 a0 = *(const u16x8*)(xb + i00 + 8 * i);
                    u16x8 a1 = *(const u16x8*)(xb + i10 + 8 * i);
                    u16x8 a2 = *(const u16x8*)(xb + i01 + 8 * i);
                    u16x8 a3 = *(const u16x8*)(xb + i11 + 8 * i);
#pragma unroll
                    for (int e = 0; e < 8; e++) {
                        v00[e] = bf2f(a0[e]); v10[e] = bf2f(a1[e]);
                        v01[e] = bf2f(a2[e]); v11[e] = bf2f(a3[e]);
                    }
                } else {
                    const float* xf = (const float*)xin;
#pragma unroll
                    for (int q = 0; q < 2; q++) {
                        v4f b0 = *(const v4f*)(xf + i00 + 8 * i + 4 * q);
                        v4f b1 = *(const v4f*)(xf + i10 + 8 * i + 4 * q);
                        v4f b2 = *(const v4f*)(xf + i01 + 8 * i + 4 * q);
                        v4f b3 = *(const v4f*)(xf + i11 + 8 * i + 4 * q);
#pragma unroll
                        for (int e = 0; e < 4; e++) {
                            v00[4 * q + e] = b0[e]; v10[4 * q + e] = b1[e];
                            v01[4 * q + e] = b2[e]; v11[4 * q + e] = b3[e];
                        }
                    }
                }
                u16x8 o;
#pragma unroll
                for (int e = 0; e < 8; e++) {
                    float vt = v00[e] + (v10[e] - v00[e]) * fy;
                    float vb = v01[e] + (v11[e] - v01[e]) * fy;
                    o[e] = f2bf(vt + (vb - vt) * fx);
                }
                int pg = (((ch >> 3) + i) ^ (p1 & 7));
                *(u16x8*)(&sA[p1 * 64 + pg * 8]) = o;
            }
        }
        __syncthreads();

        // ---- MFMA: acc[32p x 64f] += A[32p x 64c] * W[64c x 64f] ----
#pragma unroll
        for (int ks = 0; ks < 4; ks++) {            // K=16 per mfma
            int g = (ks * 2 + kh);
            u32x4 a  = *(const u32x4*)&sA[arow * 64 + ((g ^ (arow & 7)) << 3)];
            u32x4 b0 = *(const u32x4*)&sW[(lane & 31) * 64 + ((g ^ (lane & 7)) << 3)];
            u32x4 b1 = *(const u32x4*)&sW[(32 + (lane & 31)) * 64 + ((g ^ (lane & 7)) << 3)];
            bf16x8 af = __builtin_bit_cast(bf16x8, a);
            acc0 = __builtin_amdgcn_mfma_f32_32x32x16_bf16(af, __builtin_bit_cast(bf16x8, b0), acc0, 0, 0, 0);
            acc1 = __builtin_amdgcn_mfma_f32_32x32x16_bf16(af, __builtin_bit_cast(bf16x8, b1), acc1, 0, 0, 0);
        }
        __syncthreads();
    }

    // ---- epilogue: C/D layout col=lane&31, row=(reg&3)+8*(reg>>2)+4*(lane>>5) ----
    const int fcol = lane & 31;
#pragma unroll
    for (int cb = 0; cb < 2; cb++) {
        f32x16 ac = cb ? acc1 : acc0;
        float bv = cb ? bv1 : bv0;
#pragma unroll
        for (int r = 0; r < 16; r++) {
            int p  = wv * 32 + (r & 3) + 8 * (r >> 2) + 4 * kh;
            int hh = h0 + (p >> 4), ww = w0 + (p & 15);
            out[((size_t)(bb * NH + hh) * NW + ww) * NF + cb * 32 + fcol] = ac[r] + bv;
        }
    }
}

extern "C" void kernel_launch(void* const* d_in, const int* in_sizes, int n_in,
                              void* d_out, int out_size, void* d_ws, size_t ws_size,
                              hipStream_t stream) {
    const float* xin  = (const float*)d_in[0];
    const float* offs = (const float*)d_in[1];
    const float* wt   = (const float*)d_in[2];
    const float* bias = (const float*)d_in[3];
    float* out = (float*)d_out;

    const size_t xbytes = (size_t)NB * NH * NW * NC * 2;   // 16.78 MB
    const size_t wbytes = (size_t)NTAP * NC * NF * 2;      // 73.7 KB
    dim3 grid(NW / 16, NH / 8, NB);                        // 8 x 16 x 8 = 1024 blocks

    if (ws_size >= xbytes + wbytes) {
        ushort* xb   = (ushort*)d_ws;
        ushort* wimg = (ushort*)((char*)d_ws + xbytes);
        int n8 = NB * NH * NW * NC / 8;                    // 1,048,576
        cvt_x_kernel<<<n8 / 256, 256, 0, stream>>>(xin, xb);
        prep_w_kernel<<<NTAP * NC * NF / 256, 256, 0, stream>>>(wt, wimg);
        dconv2d_mfma<true><<<grid, 256, 0, stream>>>(xb, offs, wimg, bias, out);
    } else {
        dconv2d_mfma<false><<<grid, 256, 0, stream>>>(xin, offs, wt, bias, out);
    }
}

// Round 3
// 60.664 us; speedup vs baseline: 3.1919x; 1.1046x over previous
//
#include <hip/hip_runtime.h>

typedef float v4f __attribute__((ext_vector_type(4)));
typedef float v2f __attribute__((ext_vector_type(2)));
typedef unsigned int uint;
typedef unsigned short ushort;
typedef __attribute__((ext_vector_type(4))) uint u32x4;
typedef __attribute__((ext_vector_type(8))) ushort u16x8;
typedef __attribute__((ext_vector_type(8))) _Float16 h8;
typedef __attribute__((ext_vector_type(16))) float f32x16;

#define NB 8
#define NH 128
#define NW 128
#define NC 64
#define NF 64
#define NTAP 9

__device__ __forceinline__ ushort f2h(float f) {
    return __builtin_bit_cast(ushort, (_Float16)f);
}
__device__ __forceinline__ void g2lds16(const void* g, void* l) {
    __builtin_amdgcn_global_load_lds((__attribute__((address_space(1))) void*)(uintptr_t)g,
                                     (__attribute__((address_space(3))) void*)l, 16, 0, 0);
}

// ---- prep: x fp32 -> fp16 ----
__global__ __launch_bounds__(256) void cvt_x_kernel(const float* __restrict__ x,
                                                    ushort* __restrict__ xh) {
    size_t i = (size_t)blockIdx.x * 256 + threadIdx.x;     // 8 elems/thread
    const v4f* src = (const v4f*)x + 2 * i;
    v4f a = src[0], b = src[1];
    u16x8 o;
#pragma unroll
    for (int j = 0; j < 4; j++) { o[j] = f2h(a[j]); o[4 + j] = f2h(b[j]); }
    *(u16x8*)(xh + 8 * i) = o;
}

// ---- prep: W [k][c][f] fp32 -> fp16 image [k][f][c] with XOR-swizzled granules ----
__global__ __launch_bounds__(256) void prep_w_kernel(const float* __restrict__ wt,
                                                     ushort* __restrict__ wimg) {
    int idx = blockIdx.x * 256 + threadIdx.x;              // 9*64*64
    int c = idx & 63, f = (idx >> 6) & 63, k = idx >> 12;
    int pg = (c >> 3) ^ (f & 7);
    wimg[(k * 64 + f) * 64 + pg * 8 + (c & 7)] = f2h(wt[(k * 64 + c) * 64 + f]);
}

// ---- main: 128-pixel (8h x 16w) x 64-F tile; 4 waves; dbuf LDS; 1 barrier/tap ----
__global__ __launch_bounds__(256)
void dconv2d_mfma_h(const ushort* __restrict__ xh,
                    const float* __restrict__ offs,
                    const ushort* __restrict__ wimg,
                    const float* __restrict__ bias,
                    float* __restrict__ out)
{
    __shared__ ushort sA[2][128 * 64];   // 2 x 16 KB
    __shared__ ushort sW[2][64 * 64];    // 2 x 8 KB

    const int t    = threadIdx.x;
    const int id   = blockIdx.x;
    const int bb   = id & 7;             // batch == XCD (2 MB x-slice fits 4 MB L2)
    const int tile = id >> 3;
    const int h0   = (tile >> 3) * 8;
    const int w0   = (tile & 7) * 16;

    // sampling ids: 2 threads/pixel, 32 channels each
    const int p1 = t >> 1;
    const int ch = (t & 1) << 5;
    const int h  = h0 + (p1 >> 4);
    const int w  = w0 + (p1 & 15);

    // GEMM ids
    const int lane = t & 63, wv = t >> 6;
    const int arow = wv * 32 + (lane & 31);
    const int kh   = lane >> 5;

    // preload all 18 offsets (8B-aligned v2f loads; indices static after unroll)
    const float* offp = offs + ((size_t)(bb * NH + h) * NW + w) * (2 * NTAP);
    float offv[18];
#pragma unroll
    for (int j = 0; j < 9; j++) {
        v2f q = *(const v2f*)(offp + 2 * j);
        offv[2 * j] = q[0]; offv[2 * j + 1] = q[1];
    }

    auto stageW = [&](int k, int buf) {
        const char* gb = (const char*)wimg + (size_t)k * 8192;
        char* lb = (char*)(&sW[buf][0]);
#pragma unroll
        for (int it = 0; it < 2; it++)
            g2lds16(gb + it * 4096 + t * 16, lb + it * 4096 + wv * 1024);
    };

    auto issue = [&](int k, u16x8* g00, u16x8* g10, u16x8* g01, u16x8* g11,
                     float& fy, float& fx) {
        const int ky = k / 3, kx = k - 3 * ky;
        float cy = (float)(h - 1 + ky) + offv[2 * k];
        float cx = (float)(w - 1 + kx) + offv[2 * k + 1];
        cy = fminf(fmaxf(cy, 0.f), 127.f);
        cx = fminf(fmaxf(cx, 0.f), 127.f);
        float fy0 = floorf(cy), fx0 = floorf(cx);
        int y0 = (int)fy0,       x0 = (int)fx0;
        int y1 = (int)ceilf(cy), x1 = (int)ceilf(cx);
        fy = cy - fy0; fx = cx - fx0;
        int i00 = ((bb * NH + y0) * NW + x0) * NC + ch;
        int i10 = ((bb * NH + y1) * NW + x0) * NC + ch;
        int i01 = ((bb * NH + y0) * NW + x1) * NC + ch;
        int i11 = ((bb * NH + y1) * NW + x1) * NC + ch;
#pragma unroll
        for (int i = 0; i < 4; i++) {
            g00[i] = *(const u16x8*)(xh + i00 + 8 * i);
            g10[i] = *(const u16x8*)(xh + i10 + 8 * i);
            g01[i] = *(const u16x8*)(xh + i01 + 8 * i);
            g11[i] = *(const u16x8*)(xh + i11 + 8 * i);
        }
    };

    auto commit = [&](int buf, u16x8* g00, u16x8* g10, u16x8* g01, u16x8* g11,
                      float fy, float fx) {
        _Float16 fyh = (_Float16)fy, fxh = (_Float16)fx;
        h8 fy8 = {fyh, fyh, fyh, fyh, fyh, fyh, fyh, fyh};
        h8 fx8 = {fxh, fxh, fxh, fxh, fxh, fxh, fxh, fxh};
#pragma unroll
        for (int i = 0; i < 4; i++) {
            h8 v00 = __builtin_bit_cast(h8, g00[i]);
            h8 v10 = __builtin_bit_cast(h8, g10[i]);
            h8 v01 = __builtin_bit_cast(h8, g01[i]);
            h8 v11 = __builtin_bit_cast(h8, g11[i]);
            h8 vt = v00 + (v10 - v00) * fy8;
            h8 vb = v01 + (v11 - v01) * fy8;
            h8 sv = vt + (vb - vt) * fx8;
            int pg = (((ch >> 3) + i) ^ (p1 & 7));
            *(u16x8*)(&sA[buf][p1 * 64 + pg * 8]) = __builtin_bit_cast(u16x8, sv);
        }
    };

    f32x16 acc0 = (f32x16)0.0f, acc1 = (f32x16)0.0f;

    auto mm = [&](int buf) {
#pragma unroll
        for (int ks = 0; ks < 4; ks++) {
            int g = ks * 2 + kh;
            u32x4 a  = *(const u32x4*)&sA[buf][arow * 64 + ((g ^ (arow & 7)) << 3)];
            u32x4 b0 = *(const u32x4*)&sW[buf][(lane & 31) * 64 + ((g ^ (lane & 7)) << 3)];
            u32x4 b1 = *(const u32x4*)&sW[buf][(32 + (lane & 31)) * 64 + ((g ^ (lane & 7)) << 3)];
            h8 af = __builtin_bit_cast(h8, a);
            acc0 = __builtin_amdgcn_mfma_f32_32x32x16_f16(af, __builtin_bit_cast(h8, b0), acc0, 0, 0, 0);
            acc1 = __builtin_amdgcn_mfma_f32_32x32x16_f16(af, __builtin_bit_cast(h8, b1), acc1, 0, 0, 0);
        }
    };

    // prologue: tap 0 into buffer 0
    stageW(0, 0);
    {
        u16x8 g00[4], g10[4], g01[4], g11[4]; float fy, fx;
        issue(0, g00, g10, g01, g11, fy, fx);
        commit(0, g00, g10, g01, g11, fy, fx);
    }
    __syncthreads();

#pragma unroll
    for (int k = 0; k < NTAP; k++) {
        const int cur = k & 1, nxt = cur ^ 1;
        u16x8 g00[4], g10[4], g01[4], g11[4]; float fy, fx;
        if (k < 8) {
            stageW(k + 1, nxt);                       // async, vmcnt
            issue(k + 1, g00, g10, g01, g11, fy, fx); // gathers in flight over MFMA
        }
        mm(cur);
        if (k < 8) {
            commit(nxt, g00, g10, g01, g11, fy, fx);
            __syncthreads();
        }
    }

    // epilogue: C/D layout col=lane&31, row=(reg&3)+8*(reg>>2)+4*(lane>>5)
    const int fcol = lane & 31;
    const float bv0 = bias[fcol], bv1 = bias[32 + fcol];
#pragma unroll
    for (int cb = 0; cb < 2; cb++) {
        f32x16 ac = cb ? acc1 : acc0;
        float bv = cb ? bv1 : bv0;
#pragma unroll
        for (int r = 0; r < 16; r++) {
            int p  = wv * 32 + (r & 3) + 8 * (r >> 2) + 4 * kh;
            int hh = h0 + (p >> 4), ww = w0 + (p & 15);
            out[((size_t)(bb * NH + hh) * NW + ww) * NF + cb * 32 + fcol] = ac[r] + bv;
        }
    }
}

// ---- fallback (ws too small): single-buffer, fp32 gathers, in-kernel W prep ----
__global__ __launch_bounds__(256)
void dconv2d_fb(const float* __restrict__ xf,
                const float* __restrict__ offs,
                const float* __restrict__ wsf,
                const float* __restrict__ bias,
                float* __restrict__ out)
{
    __shared__ ushort sA[128 * 64];
    __shared__ ushort sW[64 * 64];
    const int t  = threadIdx.x;
    const int bb = blockIdx.z;
    const int h0 = blockIdx.y * 8;
    const int w0 = blockIdx.x * 16;
    const int p1 = t >> 1, ch = (t & 1) << 5;
    const int h = h0 + (p1 >> 4), w = w0 + (p1 & 15);
    const float* offp = offs + ((size_t)(bb * NH + h) * NW + w) * (2 * NTAP);
    const int lane = t & 63, wv = t >> 6;
    const int arow = wv * 32 + (lane & 31);
    const int kh = lane >> 5;
    f32x16 acc0 = (f32x16)0.0f, acc1 = (f32x16)0.0f;

    for (int k = 0; k < NTAP; k++) {
        const float* wp = wsf + (size_t)k * 4096;
#pragma unroll
        for (int it = 0; it < 4; it++) {
            int c = it * 16 + (t >> 4);
            int f4 = (t & 15) * 4;
            v4f v = *(const v4f*)(wp + c * 64 + f4);
#pragma unroll
            for (int j = 0; j < 4; j++) {
                int f = f4 + j;
                sW[f * 64 + (((c >> 3) ^ (f & 7)) << 3) + (c & 7)] = f2h(v[j]);
            }
        }
        const int ky = k / 3, kx = k - 3 * ky;
        float cy = (float)(h - 1 + ky) + offp[2 * k];
        float cx = (float)(w - 1 + kx) + offp[2 * k + 1];
        cy = fminf(fmaxf(cy, 0.f), 127.f);
        cx = fminf(fmaxf(cx, 0.f), 127.f);
        float fy0 = floorf(cy), fx0 = floorf(cx);
        int y0 = (int)fy0, x0 = (int)fx0;
        int y1 = (int)ceilf(cy), x1 = (int)ceilf(cx);
        float fy = cy - fy0, fx = cx - fx0;
        const float* r00 = xf + ((bb * NH + y0) * NW + x0) * NC + ch;
        const float* r10 = xf + ((bb * NH + y1) * NW + x0) * NC + ch;
        const float* r01 = xf + ((bb * NH + y0) * NW + x1) * NC + ch;
        const float* r11 = xf + ((bb * NH + y1) * NW + x1) * NC + ch;
#pragma unroll
        for (int i = 0; i < 8; i++) {
            v4f v00 = *(const v4f*)(r00 + 4 * i);
            v4f v10 = *(const v4f*)(r10 + 4 * i);
            v4f v01 = *(const v4f*)(r01 + 4 * i);
            v4f v11 = *(const v4f*)(r11 + 4 * i);
            v4f vt = v00 + (v10 - v00) * fy;
            v4f vb = v01 + (v11 - v01) * fy;
            v4f sv = vt + (vb - vt) * fx;
            int g = (ch >> 3) + (i >> 1);
            int pg = g ^ (p1 & 7);
#pragma unroll
            for (int e = 0; e < 4; e++)
                sA[p1 * 64 + pg * 8 + (i & 1) * 4 + e] = f2h(sv[e]);
        }
        __syncthreads();
#pragma unroll
        for (int ks = 0; ks < 4; ks++) {
            int g = ks * 2 + kh;
            u32x4 a  = *(const u32x4*)&sA[arow * 64 + ((g ^ (arow & 7)) << 3)];
            u32x4 b0 = *(const u32x4*)&sW[(lane & 31) * 64 + ((g ^ (lane & 7)) << 3)];
            u32x4 b1 = *(const u32x4*)&sW[(32 + (lane & 31)) * 64 + ((g ^ (lane & 7)) << 3)];
            h8 af = __builtin_bit_cast(h8, a);
            acc0 = __builtin_amdgcn_mfma_f32_32x32x16_f16(af, __builtin_bit_cast(h8, b0), acc0, 0, 0, 0);
            acc1 = __builtin_amdgcn_mfma_f32_32x32x16_f16(af, __builtin_bit_cast(h8, b1), acc1, 0, 0, 0);
        }
        __syncthreads();
    }
    const int fcol = lane & 31;
    const float bv0 = bias[fcol], bv1 = bias[32 + fcol];
#pragma unroll
    for (int cb = 0; cb < 2; cb++) {
        f32x16 ac = cb ? acc1 : acc0;
        float bv = cb ? bv1 : bv0;
#pragma unroll
        for (int r = 0; r < 16; r++) {
            int p = wv * 32 + (r & 3) + 8 * (r >> 2) + 4 * kh;
            int hh = h0 + (p >> 4), ww = w0 + (p & 15);
            out[((size_t)(bb * NH + hh) * NW + ww) * NF + cb * 32 + fcol] = ac[r] + bv;
        }
    }
}

extern "C" void kernel_launch(void* const* d_in, const int* in_sizes, int n_in,
                              void* d_out, int out_size, void* d_ws, size_t ws_size,
                              hipStream_t stream) {
    const float* xin  = (const float*)d_in[0];
    const float* offs = (const float*)d_in[1];
    const float* wt   = (const float*)d_in[2];
    const float* bias = (const float*)d_in[3];
    float* out = (float*)d_out;

    const size_t xbytes = (size_t)NB * NH * NW * NC * 2;   // 16.78 MB
    const size_t wbytes = (size_t)NTAP * NC * NF * 2;      // 73.7 KB

    if (ws_size >= xbytes + wbytes) {
        ushort* xh   = (ushort*)d_ws;
        ushort* wimg = (ushort*)((char*)d_ws + xbytes);
        int n8 = NB * NH * NW * NC / 8;
        cvt_x_kernel<<<n8 / 256, 256, 0, stream>>>(xin, xh);
        prep_w_kernel<<<NTAP * NC * NF / 256, 256, 0, stream>>>(wt, wimg);
        dconv2d_mfma_h<<<1024, 256, 0, stream>>>(xh, offs, wimg, bias, out);
    } else {
        dim3 grid(NW / 16, NH / 8, NB);
        dconv2d_fb<<<grid, 256, 0, stream>>>(xin, offs, wt, bias, out);
    }
}

// Round 4
// 60.408 us; speedup vs baseline: 3.2054x; 1.0042x over previous
//
#include <hip/hip_runtime.h>

typedef float v4f __attribute__((ext_vector_type(4)));
typedef float v2f __attribute__((ext_vector_type(2)));
typedef unsigned int uint;
typedef unsigned short ushort;
typedef __attribute__((ext_vector_type(4))) uint u32x4;
typedef __attribute__((ext_vector_type(8))) ushort u16x8;
typedef __attribute__((ext_vector_type(8))) _Float16 h8;
typedef __attribute__((ext_vector_type(16))) float f32x16;

#define NB 8
#define NH 128
#define NW 128
#define NC 64
#define NF 64
#define NTAP 9

__device__ __forceinline__ ushort f2h(float f) {
    return __builtin_bit_cast(ushort, (_Float16)f);
}

// ---- prep (one launch): blocks [0,4096) convert x fp32->fp16;
//      blocks [4096,4240) build W register-fragment image:
//      wr[((k*4+ks)*2+fh)*512 + lane*8 + e] = fp16 W[k][c][f],
//      c = ks*16 + (lane>>5)*8 + e,  f = fh*32 + (lane&31).
__global__ __launch_bounds__(256)
void prep_kernel(const float* __restrict__ x, const float* __restrict__ wt,
                 ushort* __restrict__ xh, ushort* __restrict__ wr) {
    int bid = blockIdx.x;
    if (bid < 4096) {
        size_t i = (size_t)bid * 256 + threadIdx.x;        // 8 elems/thread
        const v4f* src = (const v4f*)x + 2 * i;
        v4f a = src[0], b = src[1];
        u16x8 o;
#pragma unroll
        for (int j = 0; j < 4; j++) { o[j] = f2h(a[j]); o[4 + j] = f2h(b[j]); }
        *(u16x8*)(xh + 8 * i) = o;
    } else {
        int idx = (bid - 4096) * 256 + threadIdx.x;        // 0..36863
        int e  = idx & 7;
        int ln = (idx >> 3) & 63;
        int fh = (idx >> 9) & 1;
        int ks = (idx >> 10) & 3;
        int k  = idx >> 12;
        int c  = ks * 16 + (ln >> 5) * 8 + e;
        int f  = fh * 32 + (ln & 31);
        wr[idx] = f2h(wt[(k * 64 + c) * 64 + f]);
    }
}

// ---- main: 4 waves/block, each wave FULLY independent (no __syncthreads).
// Wave wv samples and consumes pixels [32wv, 32wv+32): sA is wave-private,
// W comes from registers (coalesced loads of prep-built image).
__global__ __launch_bounds__(256, 2)
void dconv2d_nb(const ushort* __restrict__ xh,
                const float* __restrict__ offs,
                const ushort* __restrict__ wr,
                const float* __restrict__ bias,
                float* __restrict__ out)
{
    __shared__ ushort sA[4][2][32 * 64];   // [wave][buf][row*64+c] = 32 KB

    const int t    = threadIdx.x;
    const int lane = t & 63, wv = t >> 6;
    const int id   = blockIdx.x;
    const int bb   = id & 7;               // batch == XCD (x-slice L2-resident)
    const int tile = id >> 3;
    const int h0   = (tile >> 3) * 8;
    const int w0   = (tile & 7) * 16;

    // sampling ids (wave-local): lane pair per pixel
    const int lp = lane >> 1;              // local pixel 0..31
    const int ch = (lane & 1) << 5;        // channel half
    const int p  = wv * 32 + lp;
    const int h  = h0 + (p >> 4);
    const int w  = w0 + (p & 15);

    // GEMM ids
    const int kh = lane >> 5;

    ushort* A0 = &sA[wv][0][0];
    ushort* A1 = &sA[wv][1][0];

    // preload all 18 offsets for this pixel
    const float* offp = offs + ((size_t)(bb * NH + h) * NW + w) * (2 * NTAP);
    float offv[18];
#pragma unroll
    for (int j = 0; j < 9; j++) {
        v2f q = *(const v2f*)(offp + 2 * j);
        offv[2 * j] = q[0]; offv[2 * j + 1] = q[1];
    }

    u16x8 G[16];
    u32x4 WA[8], WB[8];
    float FY, FX;
    f32x16 acc0 = (f32x16)0.0f, acc1 = (f32x16)0.0f;

    auto issueG = [&](int k) {
        const int ky = k / 3, kx = k - 3 * ky;
        float cy = (float)(h - 1 + ky) + offv[2 * k];
        float cx = (float)(w - 1 + kx) + offv[2 * k + 1];
        cy = fminf(fmaxf(cy, 0.f), 127.f);
        cx = fminf(fmaxf(cx, 0.f), 127.f);
        float fy0 = floorf(cy), fx0 = floorf(cx);
        int y0 = (int)fy0,       x0 = (int)fx0;
        int y1 = (int)ceilf(cy), x1 = (int)ceilf(cx);
        FY = cy - fy0; FX = cx - fx0;
        int i00 = ((bb * NH + y0) * NW + x0) * NC + ch;
        int i10 = ((bb * NH + y1) * NW + x0) * NC + ch;
        int i01 = ((bb * NH + y0) * NW + x1) * NC + ch;
        int i11 = ((bb * NH + y1) * NW + x1) * NC + ch;
#pragma unroll
        for (int i = 0; i < 4; i++) {
            G[i]      = *(const u16x8*)(xh + i00 + 8 * i);
            G[4 + i]  = *(const u16x8*)(xh + i10 + 8 * i);
            G[8 + i]  = *(const u16x8*)(xh + i01 + 8 * i);
            G[12 + i] = *(const u16x8*)(xh + i11 + 8 * i);
        }
    };

    auto commit = [&](ushort* buf) {
        _Float16 fyh = (_Float16)FY, fxh = (_Float16)FX;
        h8 fy8 = {fyh, fyh, fyh, fyh, fyh, fyh, fyh, fyh};
        h8 fx8 = {fxh, fxh, fxh, fxh, fxh, fxh, fxh, fxh};
#pragma unroll
        for (int i = 0; i < 4; i++) {
            h8 v00 = __builtin_bit_cast(h8, G[i]);
            h8 v10 = __builtin_bit_cast(h8, G[4 + i]);
            h8 v01 = __builtin_bit_cast(h8, G[8 + i]);
            h8 v11 = __builtin_bit_cast(h8, G[12 + i]);
            h8 vt = v00 + (v10 - v00) * fy8;
            h8 vb = v01 + (v11 - v01) * fy8;
            h8 sv = vt + (vb - vt) * fx8;
            int gl = (lane & 1) * 4 + i;               // logical granule
            *(u16x8*)(&buf[lp * 64 + ((gl ^ (lp & 7)) << 3)]) =
                __builtin_bit_cast(u16x8, sv);
        }
    };

    auto loadW = [&](int k, u32x4* Wf) {
#pragma unroll
        for (int ks = 0; ks < 4; ks++)
#pragma unroll
            for (int fh = 0; fh < 2; fh++)
                Wf[ks * 2 + fh] = *(const u32x4*)(wr +
                    ((size_t)((k * 4 + ks) * 2 + fh) * 64 + lane) * 8);
    };

    auto mm = [&](const ushort* buf, const u32x4* Wf) {
        __builtin_amdgcn_s_setprio(1);
#pragma unroll
        for (int ks = 0; ks < 4; ks++) {
            int g = ks * 2 + kh;
            u32x4 a = *(const u32x4*)&buf[(lane & 31) * 64 + ((g ^ (lane & 7)) << 3)];
            h8 af = __builtin_bit_cast(h8, a);
            acc0 = __builtin_amdgcn_mfma_f32_32x32x16_f16(af,
                       __builtin_bit_cast(h8, Wf[ks * 2 + 0]), acc0, 0, 0, 0);
            acc1 = __builtin_amdgcn_mfma_f32_32x32x16_f16(af,
                       __builtin_bit_cast(h8, Wf[ks * 2 + 1]), acc1, 0, 0, 0);
        }
        __builtin_amdgcn_s_setprio(0);
    };

    // ---- per-wave software pipeline, zero barriers ----
    issueG(0); loadW(0, WA);
    commit(A0);                       // tap 0 sampled
    issueG(1); loadW(1, WB);

#pragma unroll
    for (int k = 0; k < 8; k++) {
        ushort* cb = (k & 1) ? A1 : A0;
        ushort* nb = (k & 1) ? A0 : A1;
        mm(cb, (k & 1) ? WB : WA);    // tap k
        commit(nb);                   // tap k+1 (gathers issued one tap ago)
        if (k < 7) {
            issueG(k + 2);
            loadW(k + 2, (k & 1) ? WB : WA);   // refill the set mm just consumed
        }
    }
    mm(A0, WA);                       // tap 8

    // ---- epilogue: C/D layout col=lane&31, row=(r&3)+8*(r>>2)+4*(lane>>5) ----
    const int fcol = lane & 31;
    const float bv0 = bias[fcol], bv1 = bias[32 + fcol];
#pragma unroll
    for (int cb = 0; cb < 2; cb++) {
        f32x16 ac = cb ? acc1 : acc0;
        float bv = cb ? bv1 : bv0;
#pragma unroll
        for (int r = 0; r < 16; r++) {
            int pp = wv * 32 + (r & 3) + 8 * (r >> 2) + 4 * kh;
            int hh = h0 + (pp >> 4), ww = w0 + (pp & 15);
            out[((size_t)(bb * NH + hh) * NW + ww) * NF + cb * 32 + fcol] = ac[r] + bv;
        }
    }
}

// ---- fallback (ws too small): single-buffer fp32 path with LDS W ----
__global__ __launch_bounds__(256)
void dconv2d_fb(const float* __restrict__ xf,
                const float* __restrict__ offs,
                const float* __restrict__ wsf,
                const float* __restrict__ bias,
                float* __restrict__ out)
{
    __shared__ ushort sAf[128 * 64];
    __shared__ ushort sWf[64 * 64];
    const int t  = threadIdx.x;
    const int bb = blockIdx.z;
    const int h0 = blockIdx.y * 8;
    const int w0 = blockIdx.x * 16;
    const int p1 = t >> 1, ch = (t & 1) << 5;
    const int h = h0 + (p1 >> 4), w = w0 + (p1 & 15);
    const float* offp = offs + ((size_t)(bb * NH + h) * NW + w) * (2 * NTAP);
    const int lane = t & 63, wv = t >> 6;
    const int arow = wv * 32 + (lane & 31);
    const int kh = lane >> 5;
    f32x16 acc0 = (f32x16)0.0f, acc1 = (f32x16)0.0f;

    for (int k = 0; k < NTAP; k++) {
        const float* wp = wsf + (size_t)k * 4096;
#pragma unroll
        for (int it = 0; it < 4; it++) {
            int c = it * 16 + (t >> 4);
            int f4 = (t & 15) * 4;
            v4f v = *(const v4f*)(wp + c * 64 + f4);
#pragma unroll
            for (int j = 0; j < 4; j++) {
                int f = f4 + j;
                sWf[f * 64 + (((c >> 3) ^ (f & 7)) << 3) + (c & 7)] = f2h(v[j]);
            }
        }
        const int ky = k / 3, kx = k - 3 * ky;
        float cy = (float)(h - 1 + ky) + offp[2 * k];
        float cx = (float)(w - 1 + kx) + offp[2 * k + 1];
        cy = fminf(fmaxf(cy, 0.f), 127.f);
        cx = fminf(fmaxf(cx, 0.f), 127.f);
        float fy0 = floorf(cy), fx0 = floorf(cx);
        int y0 = (int)fy0, x0 = (int)fx0;
        int y1 = (int)ceilf(cy), x1 = (int)ceilf(cx);
        float fy = cy - fy0, fx = cx - fx0;
        const float* r00 = xf + ((bb * NH + y0) * NW + x0) * NC + ch;
        const float* r10 = xf + ((bb * NH + y1) * NW + x0) * NC + ch;
        const float* r01 = xf + ((bb * NH + y0) * NW + x1) * NC + ch;
        const float* r11 = xf + ((bb * NH + y1) * NW + x1) * NC + ch;
#pragma unroll
        for (int i = 0; i < 8; i++) {
            v4f v00 = *(const v4f*)(r00 + 4 * i);
            v4f v10 = *(const v4f*)(r10 + 4 * i);
            v4f v01 = *(const v4f*)(r01 + 4 * i);
            v4f v11 = *(const v4f*)(r11 + 4 * i);
            v4f vt = v00 + (v10 - v00) * fy;
            v4f vb = v01 + (v11 - v01) * fy;
            v4f sv = vt + (vb - vt) * fx;
            int g = (ch >> 3) + (i >> 1);
            int pg = g ^ (p1 & 7);
#pragma unroll
            for (int e = 0; e < 4; e++)
                sAf[p1 * 64 + pg * 8 + (i & 1) * 4 + e] = f2h(sv[e]);
        }
        __syncthreads();
#pragma unroll
        for (int ks = 0; ks < 4; ks++) {
            int g = ks * 2 + kh;
            u32x4 a  = *(const u32x4*)&sAf[arow * 64 + ((g ^ (arow & 7)) << 3)];
            u32x4 b0 = *(const u32x4*)&sWf[(lane & 31) * 64 + ((g ^ (lane & 7)) << 3)];
            u32x4 b1 = *(const u32x4*)&sWf[(32 + (lane & 31)) * 64 + ((g ^ (lane & 7)) << 3)];
            h8 af = __builtin_bit_cast(h8, a);
            acc0 = __builtin_amdgcn_mfma_f32_32x32x16_f16(af, __builtin_bit_cast(h8, b0), acc0, 0, 0, 0);
            acc1 = __builtin_amdgcn_mfma_f32_32x32x16_f16(af, __builtin_bit_cast(h8, b1), acc1, 0, 0, 0);
        }
        __syncthreads();
    }
    const int fcol = lane & 31;
    const float bv0 = bias[fcol], bv1 = bias[32 + fcol];
#pragma unroll
    for (int cb = 0; cb < 2; cb++) {
        f32x16 ac = cb ? acc1 : acc0;
        float bv = cb ? bv1 : bv0;
#pragma unroll
        for (int r = 0; r < 16; r++) {
            int pp = wv * 32 + (r & 3) + 8 * (r >> 2) + 4 * kh;
            int hh = h0 + (pp >> 4), ww = w0 + (pp & 15);
            out[((size_t)(bb * NH + hh) * NW + ww) * NF + cb * 32 + fcol] = ac[r] + bv;
        }
    }
}

extern "C" void kernel_launch(void* const* d_in, const int* in_sizes, int n_in,
                              void* d_out, int out_size, void* d_ws, size_t ws_size,
                              hipStream_t stream) {
    const float* xin  = (const float*)d_in[0];
    const float* offs = (const float*)d_in[1];
    const float* wt   = (const float*)d_in[2];
    const float* bias = (const float*)d_in[3];
    float* out = (float*)d_out;

    const size_t xbytes = (size_t)NB * NH * NW * NC * 2;   // 16.78 MB
    const size_t wbytes = (size_t)NTAP * 4 * 2 * 64 * 8 * 2; // 73.7 KB

    if (ws_size >= xbytes + wbytes) {
        ushort* xh = (ushort*)d_ws;
        ushort* wr = (ushort*)((char*)d_ws + xbytes);
        prep_kernel<<<4096 + 144, 256, 0, stream>>>(xin, wt, xh, wr);
        dconv2d_nb<<<1024, 256, 0, stream>>>(xh, offs, wr, bias, out);
    } else {
        dim3 grid(NW / 16, NH / 8, NB);
        dconv2d_fb<<<grid, 256, 0, stream>>>(xin, offs, wt, bias, out);
    }
}